// Round 9
// baseline (299.727 us; speedup 1.0000x reference)
//
#include <hip/hip_runtime.h>
#include <stdint.h>

#define NN   2048
#define DD   128
#define DIN  256
#define ROWZ 75

typedef float f32x4 __attribute__((ext_vector_type(4)));
typedef short bf16x8 __attribute__((ext_vector_type(8)));
typedef unsigned int u32x2 __attribute__((ext_vector_type(2)));

__device__ __forceinline__ unsigned short f2bf(float x){
  union { float f; unsigned int u; } v; v.f = x;
  unsigned int u = v.u;
  u += 0x7fffu + ((u >> 16) & 1u);   // RNE
  return (unsigned short)(u >> 16);
}
__device__ __forceinline__ float bf2f(unsigned short b){
  union { float f; unsigned int u; } v; v.u = ((unsigned int)b) << 16;
  return v.f;
}

// ---------------------------------------------------------------------------
// Kernel A (R12): heterogeneous fusion — blocks 0..255 = R11's MFMA wh
// (bf16x3 split, free transposed C); blocks 256..511 = adj ballot bit-pack
// (134MB -> 4MB). ~1 wh + 1 pack block per CU: the adj HBM stream runs
// under wh's compute shadow (wh uses <1 TB/s), instead of stalling attn's
// MFMA loop. Pack layout: bit (col&31) of u32 word (col>>5), row-major.
// ---------------------------------------------------------------------------
__launch_bounds__(512, 2)
__global__ void wh_pack_kernel(const float* __restrict__ h, const float* __restrict__ W,
                               const int* __restrict__ adje,
                               unsigned short* __restrict__ whn, unsigned short* __restrict__ whT,
                               unsigned long long* __restrict__ adjp)
{
  const int t   = threadIdx.x;
  const int bid = blockIdx.x;

  if (bid >= 256){
    // ---------------- pack path: 64 global rows per block ----------------
    const int pb = bid - 256;
    const int wv = t >> 6;
    const int ln = t & 63;
#pragma unroll 1
    for (int rr = 0; rr < 8; ++rr){
      const int grow = pb * 64 + wv * 8 + rr;
      const int* arow = adje + (size_t)grow * NN;
      unsigned long long* drow = adjp + (size_t)grow * 32;
#pragma unroll 1
      for (int cb = 0; cb < 2; ++cb){
        int pv[16];
#pragma unroll
        for (int j = 0; j < 16; ++j) pv[j] = arow[(cb*16 + j) * 64 + ln];
        unsigned long long m[16];
#pragma unroll
        for (int j = 0; j < 16; ++j) m[j] = __ballot(pv[j] > 0);
        if (ln == 0){
#pragma unroll
          for (int j = 0; j < 16; ++j) drow[cb*16 + j] = m[j];
        }
      }
    }
    return;
  }

  // ---------------- wh path (R11 body, unchanged) ----------------
  __shared__ unsigned short WhiT[128][40];   // [d][k] hi, pad 40: conflict-free b128
  __shared__ unsigned short WloT[128][40];   // [d][k] lo
  __shared__ float ssp[64][3];
  __shared__ float sinv_s[64];

  const int r0   = ((bid & 7) << 11) | ((bid >> 3) << 6);  // batch=bid&7 (XCD pin)
  const int w    = t >> 6;
  const int l    = t & 63;
  const int quad = l >> 4;
  const int l16  = l & 15;
  const int wr   = (w & 3) * 16;    // wave row base 0..48
  const int nc   = (w >> 2) * 64;   // wave col half 0/64
  const int ch   = w >> 2;

  const int sd = t & 127;           // W staging: d
  const int sk = (t >> 7) * 8;      // W staging: k-octet

  f32x4 acc[4], occ[4];
#pragma unroll
  for (int ns = 0; ns < 4; ++ns){
    acc[ns] = (f32x4){0.f,0.f,0.f,0.f};
    occ[ns] = (f32x4){0.f,0.f,0.f,0.f};
  }

  float wv8[8];
#pragma unroll
  for (int j = 0; j < 8; ++j) wv8[j] = W[(size_t)(sk + j) * DD + sd];
  const float* hrow = h + (size_t)(r0 + wr + l16) * DIN;
  f32x4 hv0 = *(const f32x4*)(hrow + quad*8);
  f32x4 hv1 = *(const f32x4*)(hrow + quad*8 + 4);

  for (int kt = 0; kt < 8; ++kt){
    __syncthreads();
    {
      bf16x8 whi8, wlo8;
#pragma unroll
      for (int j = 0; j < 8; ++j){
        float x = wv8[j];
        unsigned short hb = f2bf(x);
        whi8[j] = (short)hb;
        wlo8[j] = (short)f2bf(x - bf2f(hb));
      }
      *(bf16x8*)&WhiT[sd][sk] = whi8;
      *(bf16x8*)&WloT[sd][sk] = wlo8;
    }
    bf16x8 ahi, alo;
#pragma unroll
    for (int e = 0; e < 4; ++e){
      unsigned short hb0 = f2bf(hv0[e]), hb1 = f2bf(hv1[e]);
      ahi[e]   = (short)hb0;  alo[e]   = (short)f2bf(hv0[e] - bf2f(hb0));
      ahi[4+e] = (short)hb1;  alo[4+e] = (short)f2bf(hv1[e] - bf2f(hb1));
    }
    __syncthreads();

    if (kt < 7){
      const int k0n = (kt + 1) * 32;
#pragma unroll
      for (int j = 0; j < 8; ++j) wv8[j] = W[(size_t)(k0n + sk + j) * DD + sd];
      hv0 = *(const f32x4*)(hrow + k0n + quad*8);
      hv1 = *(const f32x4*)(hrow + k0n + quad*8 + 4);
    }

#pragma unroll
    for (int ns = 0; ns < 4; ++ns){
      bf16x8 bhi = *(const bf16x8*)&WhiT[nc + ns*16 + l16][quad*8];
      bf16x8 blo = *(const bf16x8*)&WloT[nc + ns*16 + l16][quad*8];
      acc[ns] = __builtin_amdgcn_mfma_f32_16x16x32_bf16(ahi, bhi, acc[ns], 0, 0, 0);
      acc[ns] = __builtin_amdgcn_mfma_f32_16x16x32_bf16(alo, bhi, acc[ns], 0, 0, 0);
      acc[ns] = __builtin_amdgcn_mfma_f32_16x16x32_bf16(ahi, blo, acc[ns], 0, 0, 0);
      occ[ns] = __builtin_amdgcn_mfma_f32_16x16x32_bf16(bhi, ahi, occ[ns], 0, 0, 0);
      occ[ns] = __builtin_amdgcn_mfma_f32_16x16x32_bf16(bhi, alo, occ[ns], 0, 0, 0);
      occ[ns] = __builtin_amdgcn_mfma_f32_16x16x32_bf16(blo, ahi, occ[ns], 0, 0, 0);
    }
  }

#pragma unroll
  for (int r = 0; r < 4; ++r){
    float val = 0.f;
#pragma unroll
    for (int ns = 0; ns < 4; ++ns) val += acc[ns][r] * acc[ns][r];
    val += __shfl_xor(val, 1);
    val += __shfl_xor(val, 2);
    val += __shfl_xor(val, 4);
    val += __shfl_xor(val, 8);
    if (l16 == 0) ssp[wr + quad*4 + r][ch] = val;
  }
  __syncthreads();
  if (t < 64){
    float ss = ssp[t][0] + ssp[t][1];
    sinv_s[t] = 1.0f / fmaxf(sqrtf(ss), 1e-12f);   // F.normalize eps semantics
  }
  __syncthreads();

  const int bb = r0 >> 11;
  const int n0 = (r0 & 2047) + wr;

#pragma unroll
  for (int ns = 0; ns < 4; ++ns)
#pragma unroll
    for (int r = 0; r < 4; ++r){
      const int row = wr + quad*4 + r;
      whn[(size_t)(r0 + row) * DD + nc + ns*16 + l16] = f2bf(acc[ns][r] * sinv_s[row]);
    }
#pragma unroll
  for (int ns = 0; ns < 4; ++ns)
#pragma unroll
    for (int r = 0; r < 4; ++r){
      const int d = nc + ns*16 + quad*4 + r;
      whT[((size_t)(bb * DD + d)) * NN + n0 + l16] = f2bf(occ[ns][r]);
    }
}

// ---------------------------------------------------------------------------
// Kernel B (R12 = R11 skeleton + packed masks): the 16 adj HBM dwords per
// thread/iter become 8 broadcast u32 mask-word loads from a 16KB/block
// L1-resident slab (word = it*4+ms, bit = f*16+l16). attn's HBM stream is
// gone; DMA staging / single-barrier pipeline unchanged (proven best).
// ---------------------------------------------------------------------------
__launch_bounds__(512, 2)
__global__ void attn_kernel(const unsigned short* __restrict__ whn,
                            const unsigned short* __restrict__ whT,
                            const unsigned int* __restrict__ adjp,
                            float* __restrict__ out)
{
  __shared__ unsigned short Kt[2][128 * 128];   // 64 KB K-tile (rows = m, cols = d)
  __shared__ unsigned short Vt[2][128 * 128];   // 64 KB V-tile (rows = d, cols = n)
  __shared__ unsigned short Pbuf[8][32 * 40];   // 20 KB per-wave P
  __shared__ float linv_s[64];

  const int t    = threadIdx.x;
  const int w    = t >> 6;
  const int l    = t & 63;
  const int quad = l >> 4;
  const int l16  = l & 15;
  const int qh   = w >> 2;            // q-half 0/1
  const int ms   = w & 3;             // m-strip 0..3
  const int b     = blockIdx.x & 7;   // XCD-pinned batch (round-robin dispatch)
  const int qbase = (blockIdx.x >> 3) * 64;

  const unsigned short* whn_b = whn + (size_t)b * NN * DD;
  const unsigned short* whT_b = whT + (size_t)b * DD * NN;
  const unsigned int*   mrow  = adjp + ((size_t)(b * NN + qbase + qh*32)) * 64;

#define STAGE(M0, CC)                                                          \
  if (w < 4){                                                                  \
    _Pragma("unroll")                                                          \
    for (int ii = 0; ii < 8; ++ii){                                            \
      const int row = w*32 + ii*4 + (l >> 4);                                  \
      const unsigned short* src = whn_b + (size_t)((M0) + row) * DD            \
                                  + (l16 ^ (row & 7)) * 8;                     \
      __builtin_amdgcn_global_load_lds(                                        \
          (const __attribute__((address_space(1))) void*)src,                  \
          (__attribute__((address_space(3))) void*)&Kt[CC][(w*32 + ii*4)*128], \
          16, 0, 0);                                                           \
    }                                                                          \
  } else {                                                                     \
    _Pragma("unroll")                                                          \
    for (int ii = 0; ii < 8; ++ii){                                            \
      const int dv = (w-4)*32 + ii*4 + (l >> 4);                               \
      const unsigned short* src = whT_b + (size_t)dv * NN + (M0)               \
                                  + (l16 ^ (dv & 7)) * 8;                      \
      __builtin_amdgcn_global_load_lds(                                        \
          (const __attribute__((address_space(1))) void*)src,                  \
          (__attribute__((address_space(3))) void*)&Vt[CC][((w-4)*32+ii*4)*128],\
          16, 0, 0);                                                           \
    }                                                                          \
  }

  // Q fragments
  bf16x8 qf[2][4];
#pragma unroll
  for (int s = 0; s < 2; ++s)
#pragma unroll
    for (int kc = 0; kc < 4; ++kc)
      qf[s][kc] = *(const bf16x8*)(whn_b + (size_t)(qbase + qh*32 + s*16 + l16) * DD + kc*32 + quad*8);

  f32x4 oacc[2][8];
  float lacc[2][4];
#pragma unroll
  for (int s = 0; s < 2; ++s){
#pragma unroll
    for (int dt = 0; dt < 8; ++dt) oacc[s][dt] = (f32x4){0.f, 0.f, 0.f, 0.f};
#pragma unroll
    for (int r = 0; r < 4; ++r) lacc[s][r] = 0.f;
  }

  unsigned short* const Pw = &Pbuf[w][0];

  // prologue: tiles(0)
  STAGE(0, 0)
  __syncthreads();

  for (int it = 0; it < 16; ++it){
    const int m0  = it * 128;
    const int cur = it & 1;

    // prefetch it+1: K/V tiles -> other LDS buffer
    if (it < 15){
      const int mn = m0 + 128;
      STAGE(mn, cur ^ 1)
    }

    // mask words for this iter: broadcast loads (16 lanes share an address),
    // 16KB slab -> L1-resident after first touch
    unsigned int mw[2][4];
#pragma unroll
    for (int s = 0; s < 2; ++s)
#pragma unroll
      for (int r = 0; r < 4; ++r)
        mw[s][r] = mrow[(size_t)(s*16 + quad*4 + r) * 64 + it*4 + ms];

    // QK from LDS K-tile + mask + exp -> P (wave-private)
    bf16x8 kf[2][4];
#pragma unroll
    for (int f = 0; f < 2; ++f)
#pragma unroll
      for (int kc = 0; kc < 4; ++kc){
        const int row = ms*32 + f*16 + l16;
        kf[f][kc] = *(const bf16x8*)&Kt[cur][row*128 + (((kc*4 + quad) ^ (l16 & 7)) * 8)];
      }
#pragma unroll
    for (int f = 0; f < 2; ++f){
#pragma unroll
      for (int s = 0; s < 2; ++s){
        f32x4 sc = (f32x4){0.f, 0.f, 0.f, 0.f};
#pragma unroll
        for (int kc = 0; kc < 4; ++kc)
          sc = __builtin_amdgcn_mfma_f32_16x16x32_bf16(qf[s][kc], kf[f][kc], sc, 0, 0, 0);
#pragma unroll
        for (int r = 0; r < 4; ++r){
          const int qrow = qbase + qh*32 + s*16 + quad*4 + r;
          float sv = (qrow < ROWZ) ? 0.f : sc[r];           // row-zeroing bug emulation
          float p32 = ((mw[s][r] >> (f*16 + l16)) & 1u) ? __expf(sv) : 0.f;
          unsigned short pb = f2bf(p32);
          lacc[s][r] += bf2f(pb);
          Pw[(s*16 + quad*4 + r) * 40 + f*16 + l16] = pb;
        }
      }
    }

    // PV: P(32q x 32m) * V(32m x 128d); vf shared across both q-subtiles
    bf16x8 pfr0 = *(const bf16x8*)&Pw[(l16) * 40 + quad*8];
    bf16x8 pfr1 = *(const bf16x8*)&Pw[(16 + l16) * 40 + quad*8];
    __builtin_amdgcn_s_setprio(1);
#pragma unroll
    for (int dt = 0; dt < 8; ++dt){
      const int d = dt*16 + l16;
      bf16x8 vf = *(const bf16x8*)&Vt[cur][d*128 + (((ms*4 + quad) ^ (l16 & 7)) * 8)];
      oacc[0][dt] = __builtin_amdgcn_mfma_f32_16x16x32_bf16(pfr0, vf, oacc[0][dt], 0, 0, 0);
      oacc[1][dt] = __builtin_amdgcn_mfma_f32_16x16x32_bf16(pfr1, vf, oacc[1][dt], 0, 0, 0);
    }
    __builtin_amdgcn_s_setprio(0);

    // single barrier: DMA(it+1) had the whole iter in flight -> vmcnt(0) ~free
    __builtin_amdgcn_sched_barrier(0);
    asm volatile("s_waitcnt vmcnt(0)" ::: "memory");
    __builtin_amdgcn_sched_barrier(0);
    __builtin_amdgcn_s_barrier();
    __builtin_amdgcn_sched_barrier(0);
  }

  // l reduction
  {
    float* fl = (float*)&Pbuf[0][0];
#pragma unroll
    for (int s = 0; s < 2; ++s)
#pragma unroll
      for (int r = 0; r < 4; ++r)
        fl[(qh*32 + s*16 + quad*4 + r) * 64 + ms*16 + l16] = lacc[s][r];
  }
  __syncthreads();
  if (t < 64){
    const float* fl = (const float*)&Pbuf[0][0];
    float sum = 0.f;
#pragma unroll
    for (int c = 0; c < 64; ++c) sum += fl[t * 64 + c];
    linv_s[t] = 1.0f / sum;
  }

  // output: reduce oacc across the 4 m-strips per q-half (Kt as scratch)
  float* const owf = (float*)&Kt[0][0];    // 64 KB: [wave][16 rows][128 d]
  for (int s = 0; s < 2; ++s){
    __syncthreads();
#pragma unroll
    for (int dt = 0; dt < 8; ++dt)
#pragma unroll
      for (int r = 0; r < 4; ++r)
        owf[w*2048 + (quad*4 + r)*128 + dt*16 + l16] = oacc[s][dt][r];
    __syncthreads();
#pragma unroll
    for (int j = 0; j < 8; ++j){
      const int o     = j*512 + t;          // 4096 = 32 rows x 128 d
      const int row32 = o >> 7;
      const int d     = o & 127;
      const int qh2   = row32 >> 4;
      const int r16   = row32 & 15;
      float v = owf[(qh2*4 + 0)*2048 + r16*128 + d]
              + owf[(qh2*4 + 1)*2048 + r16*128 + d]
              + owf[(qh2*4 + 2)*2048 + r16*128 + d]
              + owf[(qh2*4 + 3)*2048 + r16*128 + d];
      const int qrl = qh2*32 + s*16 + r16;
      v *= linv_s[qrl];
      v = (v > 0.f) ? v : expm1f(v);        // ELU (alpha=1)
      out[(size_t)(b*NN + qbase + qrl) * DD + d] = v;
    }
  }
#undef STAGE
}

extern "C" void kernel_launch(void* const* d_in, const int* in_sizes, int n_in,
                              void* d_out, int out_size, void* d_ws, size_t ws_size,
                              hipStream_t stream)
{
  const float* h       = (const float*)d_in[0];
  // d_in[1] = adj  (unused by the reference)
  const int*   adj_eye = (const int*)d_in[2];
  const float* W       = (const float*)d_in[3];
  float*       out     = (float*)d_out;

  unsigned short* whn  = (unsigned short*)d_ws;                      // 16384*128 bf16 = 4 MB
  unsigned short* whT  = whn + (size_t)16384 * 128;                  // 8*128*2048 bf16 = 4 MB
  unsigned long long* adjp = (unsigned long long*)(whT + (size_t)16384 * 128); // 16384*32 u64 = 4 MB

  wh_pack_kernel<<<512, 512, 0, stream>>>(h, W, adj_eye, whn, whT, adjp);
  attn_kernel<<<256, 512, 0, stream>>>(whn, whT, (const unsigned int*)adjp, out);
}